// Round 2
// baseline (659.437 us; speedup 1.0000x reference)
//
#include <hip/hip_runtime.h>

#define NN    100000
#define NE    1600000
#define BSH   9            // 512 nodes per bucket
#define BSZ   512
#define NBK   196          // ceil(NN/512)
#define TA    8192         // edges per binA chunk-block
#define NBA   196          // ceil(NE/TA)
#define CAP2R 8960         // per-bucket raw edge capacity (mean 8192, +8.5 sigma)
#define CAP2  9472         // per-bucket capacity incl. self-loops (CAP2R + 512)
#define NBG   782          // gemm blocks in k_front

typedef _Float16 half_t;
typedef __attribute__((ext_vector_type(2))) _Float16 f16x2;
typedef __attribute__((ext_vector_type(4))) _Float16 f16x4;
typedef __attribute__((ext_vector_type(8))) _Float16 f16x8;
typedef __attribute__((ext_vector_type(4))) float    f32x4;

// ============================ k_prep: weight transposes + att-fold rows ============================
// blocks 0..3: W1 -> WT1 rows 0..127 ([n][k] fp16); 4..7: W2 -> WT2; 8..9: Wc -> WTc (48x128)
// block 10: WT1 fold rows 128..135 = W1@att1 per head, rows 136..143 zero
// block 11: same for WT2 with att2
__global__ __launch_bounds__(256) void k_prep(const float* __restrict__ W1, const float* __restrict__ W2,
                                              const float* __restrict__ Wc,
                                              const float* __restrict__ as1, const float* __restrict__ ad1,
                                              const float* __restrict__ as2, const float* __restrict__ ad2,
                                              half_t* __restrict__ WT1, half_t* __restrict__ WT2,
                                              half_t* __restrict__ WTc) {
  __shared__ float tile[64][65];
  int b = blockIdx.x, t = threadIdx.x;
  if (b < 10) {
    const float* W; half_t* WT; int k0, n0, N, NTr;
    if (b < 4)      { W = W1; WT = WT1; k0 = (b >> 1) * 64; n0 = (b & 1) * 64; N = 128; NTr = 128; }
    else if (b < 8) { int bb = b - 4; W = W2; WT = WT2; k0 = (bb >> 1) * 64; n0 = (bb & 1) * 64; N = 128; NTr = 128; }
    else            { int bb = b - 8; W = Wc; WT = WTc; k0 = bb * 64; n0 = 0; N = 40; NTr = 48; }
    int col = t & 63, r4 = t >> 6;
#pragma unroll
    for (int i = 0; i < 16; i++) {
      int row = r4 * 16 + i;                       // k-local
      float v = 0.f;
      if (n0 + col < N) v = W[(size_t)(k0 + row) * N + n0 + col];
      tile[row][col] = v;
    }
    __syncthreads();
#pragma unroll
    for (int i = 0; i < 16; i++) {
      int nrow = r4 * 16 + i;                      // n-local
      if (n0 + nrow < NTr) WT[(size_t)(n0 + nrow) * 128 + k0 + col] = (half_t)tile[col][nrow];
    }
    return;
  }
  // fold rows
  const float* W  = (b == 10) ? W1 : W2;
  const float* as = (b == 10) ? as1 : as2;
  const float* ad = (b == 10) ? ad1 : ad2;
  half_t* WT      = (b == 10) ? WT1 : WT2;
  int e = t >> 5, kr = t & 31, h = e & 3;
  const float* att = ((e < 4) ? as : ad) + h * 32;
#pragma unroll
  for (int u = 0; u < 4; u++) {
    int k = u * 32 + kr;
    const float* wrow = W + (size_t)k * 128 + h * 32;
    float s = 0.f;
#pragma unroll
    for (int c = 0; c < 32; c += 4) {
      float4 wv = *(const float4*)(wrow + c);
      float4 av = *(const float4*)(att + c);
      s += wv.x * av.x + wv.y * av.y + wv.z * av.z + wv.w * av.w;
    }
    WT[(size_t)(128 + e) * 128 + k] = (half_t)s;
  }
  for (int u = t; u < 8 * 128; u += 256) WT[(size_t)136 * 128 + u] = (half_t)0.f;
}

// ============================ K1: fused front ============================
// blocks [0,196): binA — bin TA=8192 edges, flush per-bucket via global cursor (contiguous bpk)
// blocks [196,978): gemm1 — fp32 X -> fp16 @ WT1 (144 cols: H + fold logits)
// 978 blocks @ 4/CU = fully co-resident; no prep blocks, no tail.
__global__ __launch_bounds__(256, 4) void k_front(const float* __restrict__ X, const half_t* __restrict__ WT1,
                                                  half_t* __restrict__ H, float* __restrict__ asrc,
                                                  float* __restrict__ adst,
                                                  const int* __restrict__ src, const int* __restrict__ dst,
                                                  unsigned int* __restrict__ bpk, int* __restrict__ gcnt) {
  __shared__ __align__(16) char smem[36864];
  int t = threadIdx.x;
  int bid = blockIdx.x;

  if (bid < NBA) {
    // ---- binA role ----
    int hb = bid;
    int* hist  = (int*)smem;                  // [196]
    int* hscan = hist + NBK;                  // [196]
    int* cnt   = hscan + NBK;                 // [196]
    int* ssc   = cnt + NBK;                   // [256]
    unsigned int* staged = (unsigned int*)(ssc + 256);  // [8192]
    int e0 = hb * TA;
    if (t < NBK) { hist[t] = 0; cnt[t] = 0; }
    __syncthreads();
    for (int i = 0; i < TA / 256; i++) {
      int e = e0 + t + i * 256;
      if (e < NE) atomicAdd(&hist[dst[e] >> BSH], 1);
    }
    __syncthreads();
    // exclusive scan of hist (196 <= 256)
    {
      int v = (t < NBK) ? hist[t] : 0;
      int x = v;
      ssc[t] = x;
      for (int off = 1; off < 256; off <<= 1) {
        __syncthreads();
        int y = (t >= off) ? ssc[t - off] : 0;
        __syncthreads();
        x += y;
        ssc[t] = x;
      }
      if (t < NBK) hscan[t] = x - v;
    }
    __syncthreads();
    for (int i = 0; i < TA / 256; i++) {
      int e = e0 + t + i * 256;
      if (e < NE) {
        int d = dst[e];
        int bk = d >> BSH;
        int pos = hscan[bk] + atomicAdd(&cnt[bk], 1);
        staged[pos] = ((unsigned int)src[e] << BSH) | (unsigned int)(d & (BSZ - 1));
      }
    }
    __syncthreads();
    // contiguous flush via global per-bucket cursor
    int wave = t >> 6, lane = t & 63;
    for (int bk = wave; bk < NBK; bk += 4) {
      int c = hist[bk];
      int lo = hscan[bk];
      int base = 0;
      if (lane == 0 && c > 0) base = atomicAdd(&gcnt[bk], c);
      base = __shfl(base, 0, 64);
      int avail = CAP2R - base;
      int cw = min(c, max(avail, 0));
      size_t bb = (size_t)bk * CAP2R + base;
      for (int j = lane; j < cw; j += 64) bpk[bb + j] = staged[lo + j];
    }
    return;
  }

  // ---- gemm1 role ----
  half_t* Xt = (half_t*)smem;          // [128][40]
  half_t* Wt = Xt + 128 * 40;          // [144][40]
  int wave = t >> 6, lane = t & 63;
  int l15 = lane & 15, quad = lane >> 4;
  int rb = (bid - NBA) * 128;

  f32x4 acc[2][9];
#pragma unroll
  for (int rt = 0; rt < 2; rt++)
#pragma unroll
    for (int ct = 0; ct < 9; ct++) acc[rt][ct] = (f32x4){0.f, 0.f, 0.f, 0.f};

  for (int k0 = 0; k0 < 128; k0 += 32) {
    __syncthreads();
#pragma unroll
    for (int i = 0; i < 4; i++) {
      int lin = i * 256 + t;
      int row = lin >> 3;
      int c4 = (lin & 7) * 4;
      float4 v = make_float4(0.f, 0.f, 0.f, 0.f);
      int gr = rb + row;
      if (gr < NN) v = *(const float4*)(X + (size_t)gr * 128 + k0 + c4);
      f16x4 hv;
      hv[0] = (half_t)v.x; hv[1] = (half_t)v.y; hv[2] = (half_t)v.z; hv[3] = (half_t)v.w;
      *(f16x4*)(Xt + row * 40 + c4) = hv;
    }
#pragma unroll
    for (int i = 0; i < 3; i++) {
      int lin = i * 256 + t;
      if (lin < 576) {                     // 144 rows x 4 chunks of 8 halves
        int row = lin >> 2;
        int c8 = (lin & 3) * 8;
        *(f16x8*)(Wt + row * 40 + c8) = *(const f16x8*)(WT1 + (size_t)row * 128 + k0 + c8);
      }
    }
    __syncthreads();

    f16x8 a0 = *(const f16x8*)(Xt + (wave * 32 + l15) * 40 + quad * 8);
    f16x8 a1 = *(const f16x8*)(Xt + (wave * 32 + 16 + l15) * 40 + quad * 8);
#pragma unroll
    for (int ct = 0; ct < 9; ct++) {
      f16x8 b = *(const f16x8*)(Wt + (ct * 16 + l15) * 40 + quad * 8);
      acc[0][ct] = __builtin_amdgcn_mfma_f32_16x16x32_f16(a0, b, acc[0][ct], 0, 0, 0);
      acc[1][ct] = __builtin_amdgcn_mfma_f32_16x16x32_f16(a1, b, acc[1][ct], 0, 0, 0);
    }
  }

#pragma unroll
  for (int rt = 0; rt < 2; rt++) {
    int rbase = rb + wave * 32 + rt * 16 + quad * 4;
#pragma unroll
    for (int reg = 0; reg < 4; reg++) {
      int row = rbase + reg;
      if (row < NN) {
#pragma unroll
        for (int ct = 0; ct < 8; ct++) {
          H[(size_t)row * 128 + ct * 16 + l15] = (half_t)acc[rt][ct][reg];
        }
        if (l15 < 8) {
          float v = acc[rt][8][reg];
          if (l15 < 4) asrc[row * 4 + l15] = v;
          else         adst[row * 4 + (l15 - 4)] = v;
        }
      }
    }
  }
}

// ============================ binB: contiguous read, sort bucket by dst, emit CSR + adj ============
__global__ __launch_bounds__(512) void k_binB(const unsigned int* __restrict__ bpk,
                                              const int* __restrict__ gcnt,
                                              int* __restrict__ sbeg, int* __restrict__ send,
                                              int* __restrict__ adj) {
  __shared__ int lhist[BSZ];
  __shared__ int lscan[BSZ];
  __shared__ int lcur[BSZ];
  __shared__ int ssc[512];
  __shared__ unsigned int staged[CAP2];
  int b = blockIdx.x;
  int t = threadIdx.x;
  int nbeg = b << BSH;
  int nloc = min(BSZ, NN - nbeg);
  int adjb = b * CAP2;
  int cr = min(gcnt[b], CAP2R);
  size_t rbase = (size_t)b * CAP2R;
  lhist[t] = (t < nloc) ? 1 : 0;           // self-loop in slot 0 of each node's segment
  lcur[t] = 1;
  __syncthreads();
  // pass 1: histogram by local dst (contiguous reads)
  for (int j = t; j < cr; j += 512) atomicAdd(&lhist[bpk[rbase + j] & (BSZ - 1)], 1);
  __syncthreads();
  // exclusive scan of 512 with 512 threads
  {
    int v = lhist[t];
    int x = v;
    ssc[t] = x;
    for (int off = 1; off < 512; off <<= 1) {
      __syncthreads();
      int y = (t >= off) ? ssc[t - off] : 0;
      __syncthreads();
      x += y;
      ssc[t] = x;
    }
    lscan[t] = x - v;
  }
  __syncthreads();
  int total = lscan[BSZ - 1] + lhist[BSZ - 1];
  // per-node CSR bounds + self-loop records
  if (t < nloc) {
    int bg = adjb + lscan[t];
    sbeg[nbeg + t] = bg;
    send[nbeg + t] = bg + lhist[t];
    staged[lscan[t]] = (unsigned int)(nbeg + t);
  }
  __syncthreads();
  // pass 2: scatter edges into sorted staging (slots after the self-loop)
  for (int j = t; j < cr; j += 512) {
    unsigned int v = bpk[rbase + j];
    int dl = v & (BSZ - 1);
    int idx = lscan[dl] + atomicAdd(&lcur[dl], 1);
    if (idx < CAP2) staged[idx] = v >> BSH;
  }
  __syncthreads();
  // contiguous stream-out
  int lim = min(total, CAP2);
  for (int i = t; i < lim; i += 512) adj[adjb + i] = (int)staged[i];
}

// ============================ aggregation: 64 lanes per edge, channel-exclusive, no shuffles ======
// one wave per dst node; lane owns channels 2l,2l+1; 3-stage pipeline (s/a 3-ahead, H 2-ahead).
__global__ __launch_bounds__(256) void k_agg(const half_t* __restrict__ H, const int* __restrict__ sbeg,
                                             const int* __restrict__ send, const int* __restrict__ adj,
                                             const float* __restrict__ asrc, const float* __restrict__ adst,
                                             const float* __restrict__ bias, half_t* __restrict__ out) {
  int n = blockIdx.x * 4 + (threadIdx.x >> 6);
  if (n >= NN) return;
  int lane = threadIdx.x & 63;
  int quad = lane >> 4;            // head of channels 2*lane, 2*lane+1
  float ad = adst[(size_t)n * 4 + quad];
  float2 bv = *(const float2*)(bias + 2 * lane);
  int beg = sbeg[n], end = send[n];
  int last = end - 1;              // deg >= 1 (self-loop)

  float acc0 = 0.f, acc1 = 0.f, wsum = 0.f;

  // prologue: edges beg, beg+1, beg+2 (clamped dups are prefetch-only)
  int j1 = (beg + 1 < end) ? beg + 1 : last;
  int j2 = (beg + 2 < end) ? beg + 2 : last;
  int s0 = adj[beg];
  int sA = adj[j1];
  int s2 = adj[j2];
  float a0 = asrc[(size_t)s0 * 4 + quad];
  float a1 = asrc[(size_t)sA * 4 + quad];
  float a2 = asrc[(size_t)s2 * 4 + quad];
  f16x2 h0 = *(const f16x2*)(H + (size_t)s0 * 128 + 2 * lane);
  f16x2 h1 = *(const f16x2*)(H + (size_t)sA * 128 + 2 * lane);

  for (int i = beg; i < end; ++i) {
    // issue H for edge i+2 (s2 loaded 2 iterations ago)
    f16x2 h2 = *(const f16x2*)(H + (size_t)s2 * 128 + 2 * lane);
    // prefetch s/a for edge i+3
    int i3 = i + 3;
    int j3 = (i3 < end) ? i3 : last;
    int s3 = adj[j3];
    float a3 = asrc[(size_t)s3 * 4 + quad];
    // compute edge i
    float ev = a0 + ad;
    ev = fmaxf(ev, 0.2f * ev);
    float w = __expf(ev);
    wsum += w;
    acc0 += w * (float)h0[0];
    acc1 += w * (float)h0[1];
    // rotate pipeline
    a0 = a1; a1 = a2; a2 = a3;
    h0 = h1; h1 = h2;
    s2 = s3;
  }
  float scale = 1.0f / (wsum + 1e-16f);
  float o0 = fmaxf(acc0 * scale + bv.x, 0.f);
  float o1 = fmaxf(acc1 * scale + bv.y, 0.f);
  f16x2 o;
  o[0] = (half_t)o0;
  o[1] = (half_t)o1;
  *(f16x2*)(out + (size_t)n * 128 + 2 * lane) = o;
}

// ============================ MFMA GEMM (half input, pre-transposed W with fold cols) ============================
__global__ __launch_bounds__(256) void k_gemm_att(const half_t* __restrict__ X, const half_t* __restrict__ WT,
                                                  half_t* __restrict__ H, float* __restrict__ asrc,
                                                  float* __restrict__ adst) {
  __shared__ __align__(16) half_t Xt[128 * 40];
  __shared__ __align__(16) half_t Wt[144 * 40];
  int t = threadIdx.x;
  int wave = t >> 6, lane = t & 63;
  int l15 = lane & 15, quad = lane >> 4;
  int rb = blockIdx.x * 128;

  f32x4 acc[2][9];
#pragma unroll
  for (int rt = 0; rt < 2; rt++)
#pragma unroll
    for (int ct = 0; ct < 9; ct++) acc[rt][ct] = (f32x4){0.f, 0.f, 0.f, 0.f};

  for (int k0 = 0; k0 < 128; k0 += 32) {
    __syncthreads();
#pragma unroll
    for (int i = 0; i < 2; i++) {
      int lin = i * 256 + t;
      int row = lin >> 2;
      int c8 = (lin & 3) * 8;
      f16x8 hv = (f16x8)(half_t)0;
      int gr = rb + row;
      if (gr < NN) hv = *(const f16x8*)(X + (size_t)gr * 128 + k0 + c8);
      *(f16x8*)(Xt + row * 40 + c8) = hv;
    }
#pragma unroll
    for (int i = 0; i < 3; i++) {
      int lin = i * 256 + t;
      if (lin < 576) {                     // 144 rows x 4 chunks
        int row = lin >> 2;
        int c8 = (lin & 3) * 8;
        *(f16x8*)(Wt + row * 40 + c8) = *(const f16x8*)(WT + (size_t)row * 128 + k0 + c8);
      }
    }
    __syncthreads();

    f16x8 a0 = *(const f16x8*)(Xt + (wave * 32 + l15) * 40 + quad * 8);
    f16x8 a1 = *(const f16x8*)(Xt + (wave * 32 + 16 + l15) * 40 + quad * 8);
#pragma unroll
    for (int ct = 0; ct < 9; ct++) {
      f16x8 b = *(const f16x8*)(Wt + (ct * 16 + l15) * 40 + quad * 8);
      acc[0][ct] = __builtin_amdgcn_mfma_f32_16x16x32_f16(a0, b, acc[0][ct], 0, 0, 0);
      acc[1][ct] = __builtin_amdgcn_mfma_f32_16x16x32_f16(a1, b, acc[1][ct], 0, 0, 0);
    }
  }

#pragma unroll
  for (int rt = 0; rt < 2; rt++) {
    int rbase = rb + wave * 32 + rt * 16 + quad * 4;
#pragma unroll
    for (int reg = 0; reg < 4; reg++) {
      int row = rbase + reg;
      if (row < NN) {
#pragma unroll
        for (int ct = 0; ct < 8; ct++) {
          H[(size_t)row * 128 + ct * 16 + l15] = (half_t)acc[rt][ct][reg];
        }
        if (l15 < 8) {
          float v = acc[rt][8][reg];
          if (l15 < 4) asrc[row * 4 + l15] = v;
          else         adst[row * 4 + (l15 - 4)] = v;
        }
      }
    }
  }
}

// ============================ classifier (MFMA, Wc pre-transposed, N padded to 48) ============================
__global__ __launch_bounds__(256) void k_classifier(const half_t* __restrict__ Hf, const half_t* __restrict__ WTc,
                                                    const float* __restrict__ bc, float* __restrict__ out) {
  __shared__ __align__(16) half_t Xt[128 * 40];
  __shared__ __align__(16) half_t Wt[48 * 40];
  int t = threadIdx.x;
  int wave = t >> 6, lane = t & 63;
  int l15 = lane & 15, quad = lane >> 4;
  int rb = blockIdx.x * 128;

  f32x4 acc[2][3];
#pragma unroll
  for (int rt = 0; rt < 2; rt++)
#pragma unroll
    for (int ct = 0; ct < 3; ct++) acc[rt][ct] = (f32x4){0.f, 0.f, 0.f, 0.f};

  for (int k0 = 0; k0 < 128; k0 += 32) {
    __syncthreads();
#pragma unroll
    for (int i = 0; i < 2; i++) {
      int lin = i * 256 + t;
      int row = lin >> 2;
      int c8 = (lin & 3) * 8;
      f16x8 hv = (f16x8)(half_t)0;
      int gr = rb + row;
      if (gr < NN) hv = *(const f16x8*)(Hf + (size_t)gr * 128 + k0 + c8);
      *(f16x8*)(Xt + row * 40 + c8) = hv;
    }
    if (t < 192) {
      int row = t >> 2;
      int c8 = (t & 3) * 8;
      *(f16x8*)(Wt + row * 40 + c8) = *(const f16x8*)(WTc + (size_t)row * 128 + k0 + c8);
    }
    __syncthreads();

    f16x8 a0 = *(const f16x8*)(Xt + (wave * 32 + l15) * 40 + quad * 8);
    f16x8 a1 = *(const f16x8*)(Xt + (wave * 32 + 16 + l15) * 40 + quad * 8);
#pragma unroll
    for (int ct = 0; ct < 3; ct++) {
      f16x8 b = *(const f16x8*)(Wt + (ct * 16 + l15) * 40 + quad * 8);
      acc[0][ct] = __builtin_amdgcn_mfma_f32_16x16x32_f16(a0, b, acc[0][ct], 0, 0, 0);
      acc[1][ct] = __builtin_amdgcn_mfma_f32_16x16x32_f16(a1, b, acc[1][ct], 0, 0, 0);
    }
  }

#pragma unroll
  for (int rt = 0; rt < 2; rt++) {
#pragma unroll
    for (int ct = 0; ct < 3; ct++) {
      int col = ct * 16 + l15;
      if (col < 40) {
        float bv = bc[col];
#pragma unroll
        for (int reg = 0; reg < 4; reg++) {
          int row = rb + wave * 32 + rt * 16 + quad * 4 + reg;
          if (row < NN) out[(size_t)row * 40 + col] = acc[rt][ct][reg] + bv;
        }
      }
    }
  }
}

// ============================ launch ============================

extern "C" void kernel_launch(void* const* d_in, const int* in_sizes, int n_in,
                              void* d_out, int out_size, void* d_ws, size_t ws_size,
                              hipStream_t stream) {
  const float* x   = (const float*)d_in[0];
  const int*   ei  = (const int*)d_in[1];
  const float* W1  = (const float*)d_in[2];
  const float* as1 = (const float*)d_in[3];
  const float* ad1 = (const float*)d_in[4];
  const float* b1  = (const float*)d_in[5];
  const float* W2  = (const float*)d_in[6];
  const float* as2 = (const float*)d_in[7];
  const float* ad2 = (const float*)d_in[8];
  const float* b2  = (const float*)d_in[9];
  const float* Wc  = (const float*)d_in[10];
  const float* bc  = (const float*)d_in[11];
  float* out = (float*)d_out;

  const int* esrc = ei;
  const int* edst = ei + NE;

  char* w = (char*)d_ws;
  auto alloc = [&](size_t bytes) {
    void* p = (void*)w;
    w += (bytes + 255) & ~(size_t)255;
    return p;
  };
  half_t* A   = (half_t*)alloc(sizeof(half_t) * (size_t)NN * 128);  // gather target
  half_t* B   = (half_t*)alloc(sizeof(half_t) * (size_t)NN * 128);  // layer output
  float* asrc = (float*)alloc(sizeof(float) * (size_t)NN * 4);
  float* adst = (float*)alloc(sizeof(float) * (size_t)NN * 4);
  int* sbeg   = (int*)alloc(sizeof(int) * NN);
  int* send   = (int*)alloc(sizeof(int) * NN);
  unsigned int* bpk = (unsigned int*)alloc(sizeof(unsigned int) * (size_t)NBK * CAP2R);
  int* gcnt   = (int*)alloc(sizeof(int) * NBK);
  int* adj    = (int*)alloc(sizeof(int) * (size_t)NBK * CAP2);
  half_t* WT1 = (half_t*)alloc(sizeof(half_t) * 144 * 128);
  half_t* WT2 = (half_t*)alloc(sizeof(half_t) * 144 * 128);
  half_t* WTc = (half_t*)alloc(sizeof(half_t) * 48 * 128);

  // ---- zero per-bucket cursors (graph-capture-safe async memset) ----
  hipMemsetAsync(gcnt, 0, sizeof(int) * NBK, stream);

  // ---- weight prep (WT1 incl. layer-1 fold rows; WT2 incl. layer-2 fold; WTc) ----
  k_prep<<<12, 256, 0, stream>>>(W1, W2, Wc, as1, ad1, as2, ad2, WT1, WT2, WTc);

  // ---- fused front: binA binning + gemm1 (all co-resident) ----
  k_front<<<NBA + NBG, 256, 0, stream>>>(x, WT1, A, asrc, adst, esrc, edst, bpk, gcnt);

  // ---- CSR finalize ----
  k_binB<<<NBK, 512, 0, stream>>>(bpk, gcnt, sbeg, send, adj);

  // ---- layer 1 aggregate ----
  k_agg<<<(NN + 3) / 4, 256, 0, stream>>>(A, sbeg, send, adj, asrc, adst, b1, B);

  // ---- layer 2 ----
  k_gemm_att<<<(NN + 127) / 128, 256, 0, stream>>>(B, WT2, A, asrc, adst);
  k_agg<<<(NN + 3) / 4, 256, 0, stream>>>(A, sbeg, send, adj, asrc, adst, b2, B);

  // ---- classifier ----
  k_classifier<<<(NN + 127) / 128, 256, 0, stream>>>(B, WTc, bc, out);
}

// Round 3
// 467.163 us; speedup vs baseline: 1.4116x; 1.4116x over previous
//
#include <hip/hip_runtime.h>

#define NN    100000
#define NE    1600000
#define BSH   9            // 512 nodes per bucket
#define BSZ   512
#define NBK   196          // ceil(NN/512)
#define TA    8192         // edges per binA chunk-block
#define NBA   196          // ceil(NE/TA)
#define CAP2R 8960         // per-bucket raw edge capacity (mean 8163, +8.8 sigma)
#define CAP2  9472         // per-bucket capacity incl. self-loops (CAP2R + 512)
#define NBG   782          // gemm blocks in k_front

typedef _Float16 half_t;
typedef __attribute__((ext_vector_type(2))) _Float16 f16x2;
typedef __attribute__((ext_vector_type(4))) _Float16 f16x4;
typedef __attribute__((ext_vector_type(8))) _Float16 f16x8;
typedef __attribute__((ext_vector_type(4))) float    f32x4;

// ============================ k_prep: weight transposes + att-fold rows ============================
// blocks 0..3: W1 -> WT1 rows 0..127 ([n][k] fp16); 4..7: W2 -> WT2; 8..9: Wc -> WTc (48x128)
// block 10: WT1 fold rows 128..135 = W1@att1 per head, rows 136..143 zero
// block 11: same for WT2 with att2
__global__ __launch_bounds__(256) void k_prep(const float* __restrict__ W1, const float* __restrict__ W2,
                                              const float* __restrict__ Wc,
                                              const float* __restrict__ as1, const float* __restrict__ ad1,
                                              const float* __restrict__ as2, const float* __restrict__ ad2,
                                              half_t* __restrict__ WT1, half_t* __restrict__ WT2,
                                              half_t* __restrict__ WTc) {
  __shared__ float tile[64][65];
  int b = blockIdx.x, t = threadIdx.x;
  if (b < 10) {
    const float* W; half_t* WT; int k0, n0, N, NTr;
    if (b < 4)      { W = W1; WT = WT1; k0 = (b >> 1) * 64; n0 = (b & 1) * 64; N = 128; NTr = 128; }
    else if (b < 8) { int bb = b - 4; W = W2; WT = WT2; k0 = (bb >> 1) * 64; n0 = (bb & 1) * 64; N = 128; NTr = 128; }
    else            { int bb = b - 8; W = Wc; WT = WTc; k0 = bb * 64; n0 = 0; N = 40; NTr = 48; }
    int col = t & 63, r4 = t >> 6;
#pragma unroll
    for (int i = 0; i < 16; i++) {
      int row = r4 * 16 + i;                       // k-local
      float v = 0.f;
      if (n0 + col < N) v = W[(size_t)(k0 + row) * N + n0 + col];
      tile[row][col] = v;
    }
    __syncthreads();
#pragma unroll
    for (int i = 0; i < 16; i++) {
      int nrow = r4 * 16 + i;                      // n-local
      if (n0 + nrow < NTr) WT[(size_t)(n0 + nrow) * 128 + k0 + col] = (half_t)tile[col][nrow];
    }
    return;
  }
  // fold rows
  const float* W  = (b == 10) ? W1 : W2;
  const float* as = (b == 10) ? as1 : as2;
  const float* ad = (b == 10) ? ad1 : ad2;
  half_t* WT      = (b == 10) ? WT1 : WT2;
  int e = t >> 5, kr = t & 31, h = e & 3;
  const float* att = ((e < 4) ? as : ad) + h * 32;
#pragma unroll
  for (int u = 0; u < 4; u++) {
    int k = u * 32 + kr;
    const float* wrow = W + (size_t)k * 128 + h * 32;
    float s = 0.f;
#pragma unroll
    for (int c = 0; c < 32; c += 4) {
      float4 wv = *(const float4*)(wrow + c);
      float4 av = *(const float4*)(att + c);
      s += wv.x * av.x + wv.y * av.y + wv.z * av.z + wv.w * av.w;
    }
    WT[(size_t)(128 + e) * 128 + k] = (half_t)s;
  }
  for (int u = t; u < 8 * 128; u += 256) WT[(size_t)136 * 128 + u] = (half_t)0.f;
}

// ============================ K1: fused front ============================
// blocks [0,196): binA — bin TA=8192 edges, flush per-bucket via global cursor (contiguous bpk)
// blocks [196,978): gemm1 — fp32 X -> fp16 @ WT1 (144 cols: H + fold logits)
__global__ __launch_bounds__(256) void k_front(const float* __restrict__ X, const half_t* __restrict__ WT1,
                                               half_t* __restrict__ H, float* __restrict__ asrc,
                                               float* __restrict__ adst,
                                               const int* __restrict__ src, const int* __restrict__ dst,
                                               unsigned int* __restrict__ bpk, int* __restrict__ gcnt) {
  __shared__ __align__(16) char smem[36864];
  int t = threadIdx.x;
  int bid = blockIdx.x;

  if (bid < NBA) {
    // ---- binA role ----
    int hb = bid;
    int* hist  = (int*)smem;                  // [196]
    int* hscan = hist + NBK;                  // [196]
    int* cnt   = hscan + NBK;                 // [196]
    int* ssc   = cnt + NBK;                   // [256]
    unsigned int* staged = (unsigned int*)(ssc + 256);  // [8192]
    int e0 = hb * TA;
    if (t < NBK) { hist[t] = 0; cnt[t] = 0; }
    __syncthreads();
    for (int i = 0; i < TA / 256; i++) {
      int e = e0 + t + i * 256;
      if (e < NE) atomicAdd(&hist[dst[e] >> BSH], 1);
    }
    __syncthreads();
    // exclusive scan of hist (196 <= 256)
    {
      int v = (t < NBK) ? hist[t] : 0;
      int x = v;
      ssc[t] = x;
      for (int off = 1; off < 256; off <<= 1) {
        __syncthreads();
        int y = (t >= off) ? ssc[t - off] : 0;
        __syncthreads();
        x += y;
        ssc[t] = x;
      }
      if (t < NBK) hscan[t] = x - v;
    }
    __syncthreads();
    for (int i = 0; i < TA / 256; i++) {
      int e = e0 + t + i * 256;
      if (e < NE) {
        int d = dst[e];
        int bk = d >> BSH;
        int pos = hscan[bk] + atomicAdd(&cnt[bk], 1);
        staged[pos] = ((unsigned int)src[e] << BSH) | (unsigned int)(d & (BSZ - 1));
      }
    }
    __syncthreads();
    // contiguous flush via global per-bucket cursor
    int wave = t >> 6, lane = t & 63;
    for (int bk = wave; bk < NBK; bk += 4) {
      int c = hist[bk];
      int lo = hscan[bk];
      int base = 0;
      if (lane == 0 && c > 0) base = atomicAdd(&gcnt[bk], c);
      base = __shfl(base, 0, 64);
      int avail = CAP2R - base;
      int cw = min(c, max(avail, 0));
      size_t bb = (size_t)bk * CAP2R + base;
      for (int j = lane; j < cw; j += 64) bpk[bb + j] = staged[lo + j];
    }
    return;
  }

  // ---- gemm1 role ----
  half_t* Xt = (half_t*)smem;          // [128][40]
  half_t* Wt = Xt + 128 * 40;          // [144][40]
  int wave = t >> 6, lane = t & 63;
  int l15 = lane & 15, quad = lane >> 4;
  int rb = (bid - NBA) * 128;

  f32x4 acc[2][9];
#pragma unroll
  for (int rt = 0; rt < 2; rt++)
#pragma unroll
    for (int ct = 0; ct < 9; ct++) acc[rt][ct] = (f32x4){0.f, 0.f, 0.f, 0.f};

  for (int k0 = 0; k0 < 128; k0 += 32) {
    __syncthreads();
#pragma unroll
    for (int i = 0; i < 4; i++) {
      int lin = i * 256 + t;
      int row = lin >> 3;
      int c4 = (lin & 7) * 4;
      float4 v = make_float4(0.f, 0.f, 0.f, 0.f);
      int gr = rb + row;
      if (gr < NN) v = *(const float4*)(X + (size_t)gr * 128 + k0 + c4);
      f16x4 hv;
      hv[0] = (half_t)v.x; hv[1] = (half_t)v.y; hv[2] = (half_t)v.z; hv[3] = (half_t)v.w;
      *(f16x4*)(Xt + row * 40 + c4) = hv;
    }
#pragma unroll
    for (int i = 0; i < 3; i++) {
      int lin = i * 256 + t;
      if (lin < 576) {                     // 144 rows x 4 chunks of 8 halves
        int row = lin >> 2;
        int c8 = (lin & 3) * 8;
        *(f16x8*)(Wt + row * 40 + c8) = *(const f16x8*)(WT1 + (size_t)row * 128 + k0 + c8);
      }
    }
    __syncthreads();

    f16x8 a0 = *(const f16x8*)(Xt + (wave * 32 + l15) * 40 + quad * 8);
    f16x8 a1 = *(const f16x8*)(Xt + (wave * 32 + 16 + l15) * 40 + quad * 8);
#pragma unroll
    for (int ct = 0; ct < 9; ct++) {
      f16x8 b = *(const f16x8*)(Wt + (ct * 16 + l15) * 40 + quad * 8);
      acc[0][ct] = __builtin_amdgcn_mfma_f32_16x16x32_f16(a0, b, acc[0][ct], 0, 0, 0);
      acc[1][ct] = __builtin_amdgcn_mfma_f32_16x16x32_f16(a1, b, acc[1][ct], 0, 0, 0);
    }
  }

#pragma unroll
  for (int rt = 0; rt < 2; rt++) {
    int rbase = rb + wave * 32 + rt * 16 + quad * 4;
#pragma unroll
    for (int reg = 0; reg < 4; reg++) {
      int row = rbase + reg;
      if (row < NN) {
#pragma unroll
        for (int ct = 0; ct < 8; ct++) {
          H[(size_t)row * 128 + ct * 16 + l15] = (half_t)acc[rt][ct][reg];
        }
        if (l15 < 8) {
          float v = acc[rt][8][reg];
          if (l15 < 4) asrc[row * 4 + l15] = v;
          else         adst[row * 4 + (l15 - 4)] = v;
        }
      }
    }
  }
}

// ============================ binB: contiguous read, sort bucket by dst, emit CSR + adj ============
__global__ __launch_bounds__(512) void k_binB(const unsigned int* __restrict__ bpk,
                                              const int* __restrict__ gcnt,
                                              int* __restrict__ sbeg, int* __restrict__ send,
                                              int* __restrict__ adj) {
  __shared__ int lhist[BSZ];
  __shared__ int lscan[BSZ];
  __shared__ int lcur[BSZ];
  __shared__ int ssc[512];
  __shared__ unsigned int staged[CAP2];
  int b = blockIdx.x;
  int t = threadIdx.x;
  int nbeg = b << BSH;
  int nloc = min(BSZ, NN - nbeg);
  int adjb = b * CAP2;
  int cr = min(gcnt[b], CAP2R);
  size_t rbase = (size_t)b * CAP2R;
  lhist[t] = (t < nloc) ? 1 : 0;           // self-loop in slot 0 of each node's segment
  lcur[t] = 1;
  __syncthreads();
  // pass 1: histogram by local dst (contiguous reads)
  for (int j = t; j < cr; j += 512) atomicAdd(&lhist[bpk[rbase + j] & (BSZ - 1)], 1);
  __syncthreads();
  // exclusive scan of 512 with 512 threads
  {
    int v = lhist[t];
    int x = v;
    ssc[t] = x;
    for (int off = 1; off < 512; off <<= 1) {
      __syncthreads();
      int y = (t >= off) ? ssc[t - off] : 0;
      __syncthreads();
      x += y;
      ssc[t] = x;
    }
    lscan[t] = x - v;
  }
  __syncthreads();
  int total = lscan[BSZ - 1] + lhist[BSZ - 1];
  // per-node CSR bounds + self-loop records
  if (t < nloc) {
    int bg = adjb + lscan[t];
    sbeg[nbeg + t] = bg;
    send[nbeg + t] = bg + lhist[t];
    staged[lscan[t]] = (unsigned int)(nbeg + t);
  }
  __syncthreads();
  // pass 2: scatter edges into sorted staging (slots after the self-loop)
  for (int j = t; j < cr; j += 512) {
    unsigned int v = bpk[rbase + j];
    int dl = v & (BSZ - 1);
    int idx = lscan[dl] + atomicAdd(&lcur[dl], 1);
    if (idx < CAP2) staged[idx] = v >> BSH;
  }
  __syncthreads();
  // contiguous stream-out
  int lim = min(total, CAP2);
  for (int i = t; i < lim; i += 512) adj[adjb + i] = (int)staged[i];
}

// ============================ fused aggregation: 8 edges in flight (round-1 design, measured 76us) =
// one wave per dst node; 8 lanes x 16ch cover one 256-B row; 8 edge-groups; 1-deep prefetch.
__global__ __launch_bounds__(256) void k_agg(const half_t* __restrict__ H, const int* __restrict__ sbeg,
                                             const int* __restrict__ send, const int* __restrict__ adj,
                                             const float* __restrict__ asrc, const float* __restrict__ adst,
                                             const float* __restrict__ bias, half_t* __restrict__ out) {
  int n = blockIdx.x * 4 + (threadIdx.x >> 6);
  if (n >= NN) return;
  int lane = threadIdx.x & 63;
  int sub = lane & 7;              // 16-channel slice [sub*16, sub*16+16)
  int g = lane >> 3;               // edge group [0,8)
  int head = sub >> 1;
  float ad = adst[(size_t)n * 4 + head];
  float acc[16];
#pragma unroll
  for (int j = 0; j < 16; j++) acc[j] = 0.f;
  float wsum = 0.f;
  int beg = sbeg[n], end = send[n];
  int i = beg + g;
  int s = 0;
  float a = 0.f;
  if (i < end) {
    s = adj[i];
    a = asrc[(size_t)s * 4 + head];
  }
  while (i < end) {
    int inext = i + 8;
    int sn = 0;
    float an = 0.f;
    if (inext < end) {             // prefetch next edge's index + logit
      sn = adj[inext];
      an = asrc[(size_t)sn * 4 + head];
    }
    float ev = a + ad;
    ev = (ev > 0.f) ? ev : 0.2f * ev;
    float w = __expf(ev);
    const f16x8* hp = (const f16x8*)(H + (size_t)s * 128 + sub * 16);
    f16x8 h0 = hp[0], h1 = hp[1];
    wsum += w;
#pragma unroll
    for (int j = 0; j < 8; j++) acc[j] += w * (float)h0[j];
#pragma unroll
    for (int j = 0; j < 8; j++) acc[8 + j] += w * (float)h1[j];
    s = sn; a = an; i = inext;
  }
  // combine the 8 edge-groups (lane bits 3..5)
#pragma unroll
  for (int m = 8; m < 64; m <<= 1) {
    wsum += __shfl_xor(wsum, m, 64);
#pragma unroll
    for (int j = 0; j < 16; j++) acc[j] += __shfl_xor(acc[j], m, 64);
  }
  float scale = 1.0f / (wsum + 1e-16f);
  // lane writes channels sub*16 + g*2, +1 (full 256-B row per wave, coalesced)
  float o0 = acc[0], o1 = acc[1];
#pragma unroll
  for (int r = 1; r < 8; r++) {
    if (g == r) { o0 = acc[2 * r]; o1 = acc[2 * r + 1]; }
  }
  int ch = sub * 16 + g * 2;
  o0 = fmaxf(o0 * scale + bias[ch], 0.f);
  o1 = fmaxf(o1 * scale + bias[ch + 1], 0.f);
  f16x2 o;
  o[0] = (half_t)o0;
  o[1] = (half_t)o1;
  *(f16x2*)(out + (size_t)n * 128 + ch) = o;
}

// ============================ MFMA GEMM (half input, pre-transposed W with fold cols) ============================
__global__ __launch_bounds__(256) void k_gemm_att(const half_t* __restrict__ X, const half_t* __restrict__ WT,
                                                  half_t* __restrict__ H, float* __restrict__ asrc,
                                                  float* __restrict__ adst) {
  __shared__ __align__(16) half_t Xt[128 * 40];
  __shared__ __align__(16) half_t Wt[144 * 40];
  int t = threadIdx.x;
  int wave = t >> 6, lane = t & 63;
  int l15 = lane & 15, quad = lane >> 4;
  int rb = blockIdx.x * 128;

  f32x4 acc[2][9];
#pragma unroll
  for (int rt = 0; rt < 2; rt++)
#pragma unroll
    for (int ct = 0; ct < 9; ct++) acc[rt][ct] = (f32x4){0.f, 0.f, 0.f, 0.f};

  for (int k0 = 0; k0 < 128; k0 += 32) {
    __syncthreads();
#pragma unroll
    for (int i = 0; i < 2; i++) {
      int lin = i * 256 + t;
      int row = lin >> 2;
      int c8 = (lin & 3) * 8;
      f16x8 hv = (f16x8)(half_t)0;
      int gr = rb + row;
      if (gr < NN) hv = *(const f16x8*)(X + (size_t)gr * 128 + k0 + c8);
      *(f16x8*)(Xt + row * 40 + c8) = hv;
    }
#pragma unroll
    for (int i = 0; i < 3; i++) {
      int lin = i * 256 + t;
      if (lin < 576) {                     // 144 rows x 4 chunks
        int row = lin >> 2;
        int c8 = (lin & 3) * 8;
        *(f16x8*)(Wt + row * 40 + c8) = *(const f16x8*)(WT + (size_t)row * 128 + k0 + c8);
      }
    }
    __syncthreads();

    f16x8 a0 = *(const f16x8*)(Xt + (wave * 32 + l15) * 40 + quad * 8);
    f16x8 a1 = *(const f16x8*)(Xt + (wave * 32 + 16 + l15) * 40 + quad * 8);
#pragma unroll
    for (int ct = 0; ct < 9; ct++) {
      f16x8 b = *(const f16x8*)(Wt + (ct * 16 + l15) * 40 + quad * 8);
      acc[0][ct] = __builtin_amdgcn_mfma_f32_16x16x32_f16(a0, b, acc[0][ct], 0, 0, 0);
      acc[1][ct] = __builtin_amdgcn_mfma_f32_16x16x32_f16(a1, b, acc[1][ct], 0, 0, 0);
    }
  }

#pragma unroll
  for (int rt = 0; rt < 2; rt++) {
    int rbase = rb + wave * 32 + rt * 16 + quad * 4;
#pragma unroll
    for (int reg = 0; reg < 4; reg++) {
      int row = rbase + reg;
      if (row < NN) {
#pragma unroll
        for (int ct = 0; ct < 8; ct++) {
          H[(size_t)row * 128 + ct * 16 + l15] = (half_t)acc[rt][ct][reg];
        }
        if (l15 < 8) {
          float v = acc[rt][8][reg];
          if (l15 < 4) asrc[row * 4 + l15] = v;
          else         adst[row * 4 + (l15 - 4)] = v;
        }
      }
    }
  }
}

// ============================ classifier (MFMA, Wc pre-transposed, N padded to 48) ============================
__global__ __launch_bounds__(256) void k_classifier(const half_t* __restrict__ Hf, const half_t* __restrict__ WTc,
                                                    const float* __restrict__ bc, float* __restrict__ out) {
  __shared__ __align__(16) half_t Xt[128 * 40];
  __shared__ __align__(16) half_t Wt[48 * 40];
  int t = threadIdx.x;
  int wave = t >> 6, lane = t & 63;
  int l15 = lane & 15, quad = lane >> 4;
  int rb = blockIdx.x * 128;

  f32x4 acc[2][3];
#pragma unroll
  for (int rt = 0; rt < 2; rt++)
#pragma unroll
    for (int ct = 0; ct < 3; ct++) acc[rt][ct] = (f32x4){0.f, 0.f, 0.f, 0.f};

  for (int k0 = 0; k0 < 128; k0 += 32) {
    __syncthreads();
#pragma unroll
    for (int i = 0; i < 2; i++) {
      int lin = i * 256 + t;
      int row = lin >> 2;
      int c8 = (lin & 3) * 8;
      f16x8 hv = (f16x8)(half_t)0;
      int gr = rb + row;
      if (gr < NN) hv = *(const f16x8*)(Hf + (size_t)gr * 128 + k0 + c8);
      *(f16x8*)(Xt + row * 40 + c8) = hv;
    }
    if (t < 192) {
      int row = t >> 2;
      int c8 = (t & 3) * 8;
      *(f16x8*)(Wt + row * 40 + c8) = *(const f16x8*)(WTc + (size_t)row * 128 + k0 + c8);
    }
    __syncthreads();

    f16x8 a0 = *(const f16x8*)(Xt + (wave * 32 + l15) * 40 + quad * 8);
    f16x8 a1 = *(const f16x8*)(Xt + (wave * 32 + 16 + l15) * 40 + quad * 8);
#pragma unroll
    for (int ct = 0; ct < 3; ct++) {
      f16x8 b = *(const f16x8*)(Wt + (ct * 16 + l15) * 40 + quad * 8);
      acc[0][ct] = __builtin_amdgcn_mfma_f32_16x16x32_f16(a0, b, acc[0][ct], 0, 0, 0);
      acc[1][ct] = __builtin_amdgcn_mfma_f32_16x16x32_f16(a1, b, acc[1][ct], 0, 0, 0);
    }
  }

#pragma unroll
  for (int rt = 0; rt < 2; rt++) {
#pragma unroll
    for (int ct = 0; ct < 3; ct++) {
      int col = ct * 16 + l15;
      if (col < 40) {
        float bv = bc[col];
#pragma unroll
        for (int reg = 0; reg < 4; reg++) {
          int row = rb + wave * 32 + rt * 16 + quad * 4 + reg;
          if (row < NN) out[(size_t)row * 40 + col] = acc[rt][ct][reg] + bv;
        }
      }
    }
  }
}

// ============================ launch ============================

extern "C" void kernel_launch(void* const* d_in, const int* in_sizes, int n_in,
                              void* d_out, int out_size, void* d_ws, size_t ws_size,
                              hipStream_t stream) {
  const float* x   = (const float*)d_in[0];
  const int*   ei  = (const int*)d_in[1];
  const float* W1  = (const float*)d_in[2];
  const float* as1 = (const float*)d_in[3];
  const float* ad1 = (const float*)d_in[4];
  const float* b1  = (const float*)d_in[5];
  const float* W2  = (const float*)d_in[6];
  const float* as2 = (const float*)d_in[7];
  const float* ad2 = (const float*)d_in[8];
  const float* b2  = (const float*)d_in[9];
  const float* Wc  = (const float*)d_in[10];
  const float* bc  = (const float*)d_in[11];
  float* out = (float*)d_out;

  const int* esrc = ei;
  const int* edst = ei + NE;

  char* w = (char*)d_ws;
  auto alloc = [&](size_t bytes) {
    void* p = (void*)w;
    w += (bytes + 255) & ~(size_t)255;
    return p;
  };
  half_t* A   = (half_t*)alloc(sizeof(half_t) * (size_t)NN * 128);  // gather target
  half_t* B   = (half_t*)alloc(sizeof(half_t) * (size_t)NN * 128);  // layer output
  float* asrc = (float*)alloc(sizeof(float) * (size_t)NN * 4);
  float* adst = (float*)alloc(sizeof(float) * (size_t)NN * 4);
  int* sbeg   = (int*)alloc(sizeof(int) * NN);
  int* send   = (int*)alloc(sizeof(int) * NN);
  unsigned int* bpk = (unsigned int*)alloc(sizeof(unsigned int) * (size_t)NBK * CAP2R);
  int* gcnt   = (int*)alloc(sizeof(int) * NBK);
  int* adj    = (int*)alloc(sizeof(int) * (size_t)NBK * CAP2);
  half_t* WT1 = (half_t*)alloc(sizeof(half_t) * 144 * 128);
  half_t* WT2 = (half_t*)alloc(sizeof(half_t) * 144 * 128);
  half_t* WTc = (half_t*)alloc(sizeof(half_t) * 48 * 128);

  // ---- zero per-bucket cursors ----
  hipMemsetAsync(gcnt, 0, sizeof(int) * NBK, stream);

  // ---- weight prep (WT1 incl. layer-1 fold rows; WT2 incl. layer-2 fold; WTc) ----
  k_prep<<<12, 256, 0, stream>>>(W1, W2, Wc, as1, ad1, as2, ad2, WT1, WT2, WTc);

  // ---- fused front: binA binning + gemm1 ----
  k_front<<<NBA + NBG, 256, 0, stream>>>(x, WT1, A, asrc, adst, esrc, edst, bpk, gcnt);

  // ---- CSR finalize ----
  k_binB<<<NBK, 512, 0, stream>>>(bpk, gcnt, sbeg, send, adj);

  // ---- layer 1 aggregate ----
  k_agg<<<(NN + 3) / 4, 256, 0, stream>>>(A, sbeg, send, adj, asrc, adst, b1, B);

  // ---- layer 2 ----
  k_gemm_att<<<(NN + 127) / 128, 256, 0, stream>>>(B, WT2, A, asrc, adst);
  k_agg<<<(NN + 3) / 4, 256, 0, stream>>>(A, sbeg, send, adj, asrc, adst, b2, B);

  // ---- classifier ----
  k_classifier<<<(NN + 127) / 128, 256, 0, stream>>>(B, WTc, bc, out);
}

// Round 6
// 358.592 us; speedup vs baseline: 1.8390x; 1.3028x over previous
//
#include <hip/hip_runtime.h>

#define NN    100000
#define NE    1600000
#define BSH   9            // 512 nodes per bucket
#define BSZ   512
#define NBK   196          // ceil(NN/512)
#define TA    8192         // edges per binA chunk-block
#define NBA   196          // ceil(NE/TA)
#define CAP2R 8960         // per-bucket raw edge capacity (mean 8163, +8.8 sigma)
#define CAP2  9472         // per-bucket capacity incl. self-loops (CAP2R + 512)
#define NBG   782          // gemm blocks in k_front

typedef _Float16 half_t;
typedef __attribute__((ext_vector_type(2))) _Float16 f16x2;
typedef __attribute__((ext_vector_type(4))) _Float16 f16x4;
typedef __attribute__((ext_vector_type(8))) _Float16 f16x8;
typedef __attribute__((ext_vector_type(4))) float    f32x4;

// ============================ k_prep: weight transposes + att-fold rows ============================
__global__ __launch_bounds__(256) void k_prep(const float* __restrict__ W1, const float* __restrict__ W2,
                                              const float* __restrict__ Wc,
                                              const float* __restrict__ as1, const float* __restrict__ ad1,
                                              const float* __restrict__ as2, const float* __restrict__ ad2,
                                              half_t* __restrict__ WT1, half_t* __restrict__ WT2,
                                              half_t* __restrict__ WTc) {
  __shared__ float tile[64][65];
  int b = blockIdx.x, t = threadIdx.x;
  if (b < 10) {
    const float* W; half_t* WT; int k0, n0, N, NTr;
    if (b < 4)      { W = W1; WT = WT1; k0 = (b >> 1) * 64; n0 = (b & 1) * 64; N = 128; NTr = 128; }
    else if (b < 8) { int bb = b - 4; W = W2; WT = WT2; k0 = (bb >> 1) * 64; n0 = (bb & 1) * 64; N = 128; NTr = 128; }
    else            { int bb = b - 8; W = Wc; WT = WTc; k0 = bb * 64; n0 = 0; N = 40; NTr = 48; }
    int col = t & 63, r4 = t >> 6;
#pragma unroll
    for (int i = 0; i < 16; i++) {
      int row = r4 * 16 + i;                       // k-local
      float v = 0.f;
      if (n0 + col < N) v = W[(size_t)(k0 + row) * N + n0 + col];
      tile[row][col] = v;
    }
    __syncthreads();
#pragma unroll
    for (int i = 0; i < 16; i++) {
      int nrow = r4 * 16 + i;                      // n-local
      if (n0 + nrow < NTr) WT[(size_t)(n0 + nrow) * 128 + k0 + col] = (half_t)tile[col][nrow];
    }
    return;
  }
  // fold rows: WT rows 128..135 = W @ att per head; rows 136..143 zero
  const float* W  = (b == 10) ? W1 : W2;
  const float* as = (b == 10) ? as1 : as2;
  const float* ad = (b == 10) ? ad1 : ad2;
  half_t* WT      = (b == 10) ? WT1 : WT2;
  int e = t >> 5, kr = t & 31, h = e & 3;
  const float* att = ((e < 4) ? as : ad) + h * 32;
#pragma unroll
  for (int u = 0; u < 4; u++) {
    int k = u * 32 + kr;
    const float* wrow = W + (size_t)k * 128 + h * 32;
    float s = 0.f;
#pragma unroll
    for (int c = 0; c < 32; c += 4) {
      float4 wv = *(const float4*)(wrow + c);
      float4 av = *(const float4*)(att + c);
      s += wv.x * av.x + wv.y * av.y + wv.z * av.z + wv.w * av.w;
    }
    WT[(size_t)(128 + e) * 128 + k] = (half_t)s;
  }
  for (int u = t; u < 8 * 128; u += 256) WT[(size_t)136 * 128 + u] = (half_t)0.f;
}

// ============================ K1: fused front ============================
// blocks [0,196): binA — bin TA=8192 edges; single concurrent-atomic reservation phase
//                 (196 independent atomics, ONE latency round-trip), then atomic-free flush.
// blocks [196,978): gemm1 — fp32 X -> fp16 @ WT1 (144 cols: H + fold logits)
__global__ __launch_bounds__(256) void k_front(const float* __restrict__ X, const half_t* __restrict__ WT1,
                                               half_t* __restrict__ H, float* __restrict__ asrc,
                                               float* __restrict__ adst,
                                               const int* __restrict__ src, const int* __restrict__ dst,
                                               unsigned int* __restrict__ bpk, int* __restrict__ gcnt) {
  __shared__ __align__(16) char smem[36864];
  int t = threadIdx.x;
  int bid = blockIdx.x;

  if (bid < NBA) {
    // ---- binA role ----
    int hb = bid;
    int* hist  = (int*)smem;                  // [196]
    int* hscan = hist + NBK;                  // [196]
    int* cnt   = hscan + NBK;                 // [196] scatter cursor; reused as gbase after scatter
    int* ssc   = cnt + NBK;                   // [256]
    unsigned int* staged = (unsigned int*)(ssc + 256);  // [8192]
    int e0 = hb * TA;
    if (t < NBK) { hist[t] = 0; cnt[t] = 0; }
    __syncthreads();
    for (int i = 0; i < TA / 256; i++) {
      int e = e0 + t + i * 256;
      if (e < NE) atomicAdd(&hist[dst[e] >> BSH], 1);
    }
    __syncthreads();
    // exclusive scan of hist (196 <= 256)
    {
      int v = (t < NBK) ? hist[t] : 0;
      int x = v;
      ssc[t] = x;
      for (int off = 1; off < 256; off <<= 1) {
        __syncthreads();
        int y = (t >= off) ? ssc[t - off] : 0;
        __syncthreads();
        x += y;
        ssc[t] = x;
      }
      if (t < NBK) hscan[t] = x - v;
    }
    __syncthreads();
    for (int i = 0; i < TA / 256; i++) {
      int e = e0 + t + i * 256;
      if (e < NE) {
        int d = dst[e];
        int bk = d >> BSH;
        int pos = hscan[bk] + atomicAdd(&cnt[bk], 1);
        staged[pos] = ((unsigned int)src[e] << BSH) | (unsigned int)(d & (BSZ - 1));
      }
    }
    __syncthreads();
    // ---- concurrent cursor reservation: 196 independent atomics, ONE round-trip ----
    // cnt[] is dead after the scatter barrier; reuse it to hold the global base.
    if (t < NBK) {
      int c = hist[t];
      cnt[t] = (c > 0) ? atomicAdd(&gcnt[t], c) : 0;
    }
    __syncthreads();
    // ---- atomic-free flush into contiguous per-bucket region ----
    int wave = t >> 6, lane = t & 63;
    for (int bk = wave; bk < NBK; bk += 4) {
      int c = hist[bk];
      int lo = hscan[bk];
      int base = cnt[bk];
      int avail = CAP2R - base;
      int cw = min(c, max(avail, 0));
      size_t bb = (size_t)bk * CAP2R + base;
      for (int j = lane; j < cw; j += 64) bpk[bb + j] = staged[lo + j];
    }
    return;
  }

  // ---- gemm1 role ----
  half_t* Xt = (half_t*)smem;          // [128][40]
  half_t* Wt = Xt + 128 * 40;          // [144][40]
  int wave = t >> 6, lane = t & 63;
  int l15 = lane & 15, quad = lane >> 4;
  int rb = (bid - NBA) * 128;

  f32x4 acc[2][9];
#pragma unroll
  for (int rt = 0; rt < 2; rt++)
#pragma unroll
    for (int ct = 0; ct < 9; ct++) acc[rt][ct] = (f32x4){0.f, 0.f, 0.f, 0.f};

  for (int k0 = 0; k0 < 128; k0 += 32) {
    __syncthreads();
#pragma unroll
    for (int i = 0; i < 4; i++) {
      int lin = i * 256 + t;
      int row = lin >> 3;
      int c4 = (lin & 7) * 4;
      float4 v = make_float4(0.f, 0.f, 0.f, 0.f);
      int gr = rb + row;
      if (gr < NN) v = *(const float4*)(X + (size_t)gr * 128 + k0 + c4);
      f16x4 hv;
      hv[0] = (half_t)v.x; hv[1] = (half_t)v.y; hv[2] = (half_t)v.z; hv[3] = (half_t)v.w;
      *(f16x4*)(Xt + row * 40 + c4) = hv;
    }
#pragma unroll
    for (int i = 0; i < 3; i++) {
      int lin = i * 256 + t;
      if (lin < 576) {                     // 144 rows x 4 chunks of 8 halves
        int row = lin >> 2;
        int c8 = (lin & 3) * 8;
        *(f16x8*)(Wt + row * 40 + c8) = *(const f16x8*)(WT1 + (size_t)row * 128 + k0 + c8);
      }
    }
    __syncthreads();

    f16x8 a0 = *(const f16x8*)(Xt + (wave * 32 + l15) * 40 + quad * 8);
    f16x8 a1 = *(const f16x8*)(Xt + (wave * 32 + 16 + l15) * 40 + quad * 8);
#pragma unroll
    for (int ct = 0; ct < 9; ct++) {
      f16x8 b = *(const f16x8*)(Wt + (ct * 16 + l15) * 40 + quad * 8);
      acc[0][ct] = __builtin_amdgcn_mfma_f32_16x16x32_f16(a0, b, acc[0][ct], 0, 0, 0);
      acc[1][ct] = __builtin_amdgcn_mfma_f32_16x16x32_f16(a1, b, acc[1][ct], 0, 0, 0);
    }
  }

#pragma unroll
  for (int rt = 0; rt < 2; rt++) {
    int rbase = rb + wave * 32 + rt * 16 + quad * 4;
#pragma unroll
    for (int reg = 0; reg < 4; reg++) {
      int row = rbase + reg;
      if (row < NN) {
#pragma unroll
        for (int ct = 0; ct < 8; ct++) {
          H[(size_t)row * 128 + ct * 16 + l15] = (half_t)acc[rt][ct][reg];
        }
        if (l15 < 8) {
          float v = acc[rt][8][reg];
          if (l15 < 4) asrc[row * 4 + l15] = v;
          else         adst[row * 4 + (l15 - 4)] = v;
        }
      }
    }
  }
}

// ============================ binB: contiguous read, sort bucket by dst, emit CSR + adj ============
__global__ __launch_bounds__(512) void k_binB(const unsigned int* __restrict__ bpk,
                                              const int* __restrict__ gcnt,
                                              int* __restrict__ sbeg, int* __restrict__ send,
                                              int* __restrict__ adj) {
  __shared__ int lhist[BSZ];
  __shared__ int lscan[BSZ];
  __shared__ int lcur[BSZ];
  __shared__ int ssc[512];
  __shared__ unsigned int staged[CAP2];
  int b = blockIdx.x;
  int t = threadIdx.x;
  int nbeg = b << BSH;
  int nloc = min(BSZ, NN - nbeg);
  int adjb = b * CAP2;
  int cr = min(gcnt[b], CAP2R);
  size_t rbase = (size_t)b * CAP2R;
  lhist[t] = (t < nloc) ? 1 : 0;           // self-loop in slot 0 of each node's segment
  lcur[t] = 1;
  __syncthreads();
  // pass 1: histogram by local dst (contiguous reads)
  for (int j = t; j < cr; j += 512) atomicAdd(&lhist[bpk[rbase + j] & (BSZ - 1)], 1);
  __syncthreads();
  // exclusive scan of 512 with 512 threads
  {
    int v = lhist[t];
    int x = v;
    ssc[t] = x;
    for (int off = 1; off < 512; off <<= 1) {
      __syncthreads();
      int y = (t >= off) ? ssc[t - off] : 0;
      __syncthreads();
      x += y;
      ssc[t] = x;
    }
    lscan[t] = x - v;
  }
  __syncthreads();
  int total = lscan[BSZ - 1] + lhist[BSZ - 1];
  // per-node CSR bounds + self-loop records
  if (t < nloc) {
    int bg = adjb + lscan[t];
    sbeg[nbeg + t] = bg;
    send[nbeg + t] = bg + lhist[t];
    staged[lscan[t]] = (unsigned int)(nbeg + t);
  }
  __syncthreads();
  // pass 2: scatter edges into sorted staging (slots after the self-loop)
  for (int j = t; j < cr; j += 512) {
    unsigned int v = bpk[rbase + j];
    int dl = v & (BSZ - 1);
    int idx = lscan[dl] + atomicAdd(&lcur[dl], 1);
    if (idx < CAP2) staged[idx] = v >> BSH;
  }
  __syncthreads();
  // contiguous stream-out
  int lim = min(total, CAP2);
  for (int i = t; i < lim; i += 512) adj[adjb + i] = (int)staged[i];
}

// ============================ fused aggregation: 8 edges in flight (round-1 design, measured 76us) =
__global__ __launch_bounds__(256) void k_agg(const half_t* __restrict__ H, const int* __restrict__ sbeg,
                                             const int* __restrict__ send, const int* __restrict__ adj,
                                             const float* __restrict__ asrc, const float* __restrict__ adst,
                                             const float* __restrict__ bias, half_t* __restrict__ out) {
  int n = blockIdx.x * 4 + (threadIdx.x >> 6);
  if (n >= NN) return;
  int lane = threadIdx.x & 63;
  int sub = lane & 7;              // 16-channel slice [sub*16, sub*16+16)
  int g = lane >> 3;               // edge group [0,8)
  int head = sub >> 1;
  float ad = adst[(size_t)n * 4 + head];
  float acc[16];
#pragma unroll
  for (int j = 0; j < 16; j++) acc[j] = 0.f;
  float wsum = 0.f;
  int beg = sbeg[n], end = send[n];
  int i = beg + g;
  int s = 0;
  float a = 0.f;
  if (i < end) {
    s = adj[i];
    a = asrc[(size_t)s * 4 + head];
  }
  while (i < end) {
    int inext = i + 8;
    int sn = 0;
    float an = 0.f;
    if (inext < end) {             // prefetch next edge's index + logit
      sn = adj[inext];
      an = asrc[(size_t)sn * 4 + head];
    }
    float ev = a + ad;
    ev = (ev > 0.f) ? ev : 0.2f * ev;
    float w = __expf(ev);
    const f16x8* hp = (const f16x8*)(H + (size_t)s * 128 + sub * 16);
    f16x8 h0 = hp[0], h1 = hp[1];
    wsum += w;
#pragma unroll
    for (int j = 0; j < 8; j++) acc[j] += w * (float)h0[j];
#pragma unroll
    for (int j = 0; j < 8; j++) acc[8 + j] += w * (float)h1[j];
    s = sn; a = an; i = inext;
  }
  // combine the 8 edge-groups (lane bits 3..5)
#pragma unroll
  for (int m = 8; m < 64; m <<= 1) {
    wsum += __shfl_xor(wsum, m, 64);
#pragma unroll
    for (int j = 0; j < 16; j++) acc[j] += __shfl_xor(acc[j], m, 64);
  }
  float scale = 1.0f / (wsum + 1e-16f);
  float o0 = acc[0], o1 = acc[1];
#pragma unroll
  for (int r = 1; r < 8; r++) {
    if (g == r) { o0 = acc[2 * r]; o1 = acc[2 * r + 1]; }
  }
  int ch = sub * 16 + g * 2;
  o0 = fmaxf(o0 * scale + bias[ch], 0.f);
  o1 = fmaxf(o1 * scale + bias[ch + 1], 0.f);
  f16x2 o;
  o[0] = (half_t)o0;
  o[1] = (half_t)o1;
  *(f16x2*)(out + (size_t)n * 128 + ch) = o;
}

// ============================ MFMA GEMM (half input, pre-transposed W with fold cols) ============================
__global__ __launch_bounds__(256) void k_gemm_att(const half_t* __restrict__ X, const half_t* __restrict__ WT,
                                                  half_t* __restrict__ H, float* __restrict__ asrc,
                                                  float* __restrict__ adst) {
  __shared__ __align__(16) half_t Xt[128 * 40];
  __shared__ __align__(16) half_t Wt[144 * 40];
  int t = threadIdx.x;
  int wave = t >> 6, lane = t & 63;
  int l15 = lane & 15, quad = lane >> 4;
  int rb = blockIdx.x * 128;

  f32x4 acc[2][9];
#pragma unroll
  for (int rt = 0; rt < 2; rt++)
#pragma unroll
    for (int ct = 0; ct < 9; ct++) acc[rt][ct] = (f32x4){0.f, 0.f, 0.f, 0.f};

  for (int k0 = 0; k0 < 128; k0 += 32) {
    __syncthreads();
#pragma unroll
    for (int i = 0; i < 2; i++) {
      int lin = i * 256 + t;
      int row = lin >> 2;
      int c8 = (lin & 3) * 8;
      f16x8 hv = (f16x8)(half_t)0;
      int gr = rb + row;
      if (gr < NN) hv = *(const f16x8*)(X + (size_t)gr * 128 + k0 + c8);
      *(f16x8*)(Xt + row * 40 + c8) = hv;
    }
#pragma unroll
    for (int i = 0; i < 3; i++) {
      int lin = i * 256 + t;
      if (lin < 576) {                     // 144 rows x 4 chunks
        int row = lin >> 2;
        int c8 = (lin & 3) * 8;
        *(f16x8*)(Wt + row * 40 + c8) = *(const f16x8*)(WT + (size_t)row * 128 + k0 + c8);
      }
    }
    __syncthreads();

    f16x8 a0 = *(const f16x8*)(Xt + (wave * 32 + l15) * 40 + quad * 8);
    f16x8 a1 = *(const f16x8*)(Xt + (wave * 32 + 16 + l15) * 40 + quad * 8);
#pragma unroll
    for (int ct = 0; ct < 9; ct++) {
      f16x8 b = *(const f16x8*)(Wt + (ct * 16 + l15) * 40 + quad * 8);
      acc[0][ct] = __builtin_amdgcn_mfma_f32_16x16x32_f16(a0, b, acc[0][ct], 0, 0, 0);
      acc[1][ct] = __builtin_amdgcn_mfma_f32_16x16x32_f16(a1, b, acc[1][ct], 0, 0, 0);
    }
  }

#pragma unroll
  for (int rt = 0; rt < 2; rt++) {
    int rbase = rb + wave * 32 + rt * 16 + quad * 4;
#pragma unroll
    for (int reg = 0; reg < 4; reg++) {
      int row = rbase + reg;
      if (row < NN) {
#pragma unroll
        for (int ct = 0; ct < 8; ct++) {
          H[(size_t)row * 128 + ct * 16 + l15] = (half_t)acc[rt][ct][reg];
        }
        if (l15 < 8) {
          float v = acc[rt][8][reg];
          if (l15 < 4) asrc[row * 4 + l15] = v;
          else         adst[row * 4 + (l15 - 4)] = v;
        }
      }
    }
  }
}

// ============================ classifier (MFMA, Wc pre-transposed, N padded to 48) ============================
__global__ __launch_bounds__(256) void k_classifier(const half_t* __restrict__ Hf, const half_t* __restrict__ WTc,
                                                    const float* __restrict__ bc, float* __restrict__ out) {
  __shared__ __align__(16) half_t Xt[128 * 40];
  __shared__ __align__(16) half_t Wt[48 * 40];
  int t = threadIdx.x;
  int wave = t >> 6, lane = t & 63;
  int l15 = lane & 15, quad = lane >> 4;
  int rb = blockIdx.x * 128;

  f32x4 acc[2][3];
#pragma unroll
  for (int rt = 0; rt < 2; rt++)
#pragma unroll
    for (int ct = 0; ct < 3; ct++) acc[rt][ct] = (f32x4){0.f, 0.f, 0.f, 0.f};

  for (int k0 = 0; k0 < 128; k0 += 32) {
    __syncthreads();
#pragma unroll
    for (int i = 0; i < 2; i++) {
      int lin = i * 256 + t;
      int row = lin >> 2;
      int c8 = (lin & 3) * 8;
      f16x8 hv = (f16x8)(half_t)0;
      int gr = rb + row;
      if (gr < NN) hv = *(const f16x8*)(Hf + (size_t)gr * 128 + k0 + c8);
      *(f16x8*)(Xt + row * 40 + c8) = hv;
    }
    if (t < 192) {
      int row = t >> 2;
      int c8 = (t & 3) * 8;
      *(f16x8*)(Wt + row * 40 + c8) = *(const f16x8*)(WTc + (size_t)row * 128 + k0 + c8);
    }
    __syncthreads();

    f16x8 a0 = *(const f16x8*)(Xt + (wave * 32 + l15) * 40 + quad * 8);
    f16x8 a1 = *(const f16x8*)(Xt + (wave * 32 + 16 + l15) * 40 + quad * 8);
#pragma unroll
    for (int ct = 0; ct < 3; ct++) {
      f16x8 b = *(const f16x8*)(Wt + (ct * 16 + l15) * 40 + quad * 8);
      acc[0][ct] = __builtin_amdgcn_mfma_f32_16x16x32_f16(a0, b, acc[0][ct], 0, 0, 0);
      acc[1][ct] = __builtin_amdgcn_mfma_f32_16x16x32_f16(a1, b, acc[1][ct], 0, 0, 0);
    }
  }

#pragma unroll
  for (int rt = 0; rt < 2; rt++) {
#pragma unroll
    for (int ct = 0; ct < 3; ct++) {
      int col = ct * 16 + l15;
      if (col < 40) {
        float bv = bc[col];
#pragma unroll
        for (int reg = 0; reg < 4; reg++) {
          int row = rb + wave * 32 + rt * 16 + quad * 4 + reg;
          if (row < NN) out[(size_t)row * 40 + col] = acc[rt][ct][reg] + bv;
        }
      }
    }
  }
}

// ============================ launch ============================

extern "C" void kernel_launch(void* const* d_in, const int* in_sizes, int n_in,
                              void* d_out, int out_size, void* d_ws, size_t ws_size,
                              hipStream_t stream) {
  const float* x   = (const float*)d_in[0];
  const int*   ei  = (const int*)d_in[1];
  const float* W1  = (const float*)d_in[2];
  const float* as1 = (const float*)d_in[3];
  const float* ad1 = (const float*)d_in[4];
  const float* b1  = (const float*)d_in[5];
  const float* W2  = (const float*)d_in[6];
  const float* as2 = (const float*)d_in[7];
  const float* ad2 = (const float*)d_in[8];
  const float* b2  = (const float*)d_in[9];
  const float* Wc  = (const float*)d_in[10];
  const float* bc  = (const float*)d_in[11];
  float* out = (float*)d_out;

  const int* esrc = ei;
  const int* edst = ei + NE;

  char* w = (char*)d_ws;
  auto alloc = [&](size_t bytes) {
    void* p = (void*)w;
    w += (bytes + 255) & ~(size_t)255;
    return p;
  };
  half_t* A   = (half_t*)alloc(sizeof(half_t) * (size_t)NN * 128);  // gather target
  half_t* B   = (half_t*)alloc(sizeof(half_t) * (size_t)NN * 128);  // layer output
  float* asrc = (float*)alloc(sizeof(float) * (size_t)NN * 4);
  float* adst = (float*)alloc(sizeof(float) * (size_t)NN * 4);
  int* sbeg   = (int*)alloc(sizeof(int) * NN);
  int* send   = (int*)alloc(sizeof(int) * NN);
  unsigned int* bpk = (unsigned int*)alloc(sizeof(unsigned int) * (size_t)NBK * CAP2R);
  int* gcnt   = (int*)alloc(sizeof(int) * NBK);
  int* adj    = (int*)alloc(sizeof(int) * (size_t)NBK * CAP2);
  half_t* WT1 = (half_t*)alloc(sizeof(half_t) * 144 * 128);
  half_t* WT2 = (half_t*)alloc(sizeof(half_t) * 144 * 128);
  half_t* WTc = (half_t*)alloc(sizeof(half_t) * 48 * 128);

  // ---- zero per-bucket cursors ----
  hipMemsetAsync(gcnt, 0, sizeof(int) * NBK, stream);

  // ---- weight prep (WT1 incl. layer-1 fold rows; WT2 incl. layer-2 fold; WTc) ----
  k_prep<<<12, 256, 0, stream>>>(W1, W2, Wc, as1, ad1, as2, ad2, WT1, WT2, WTc);

  // ---- fused front: binA binning + gemm1 ----
  k_front<<<NBA + NBG, 256, 0, stream>>>(x, WT1, A, asrc, adst, esrc, edst, bpk, gcnt);

  // ---- CSR finalize ----
  k_binB<<<NBK, 512, 0, stream>>>(bpk, gcnt, sbeg, send, adj);

  // ---- layer 1 aggregate ----
  k_agg<<<(NN + 3) / 4, 256, 0, stream>>>(A, sbeg, send, adj, asrc, adst, b1, B);

  // ---- layer 2 ----
  k_gemm_att<<<(NN + 127) / 128, 256, 0, stream>>>(B, WT2, A, asrc, adst);
  k_agg<<<(NN + 3) / 4, 256, 0, stream>>>(A, sbeg, send, adj, asrc, adst, b2, B);

  // ---- classifier ----
  k_classifier<<<(NN + 127) / 128, 256, 0, stream>>>(B, WTc, bc, out);
}

// Round 7
// 353.523 us; speedup vs baseline: 1.8653x; 1.0143x over previous
//
#include <hip/hip_runtime.h>

#define NN    100000
#define NE    1600000
#define BSH   9            // 512 nodes per bucket
#define BSZ   512
#define NBK   196          // ceil(NN/512)
#define TA    8192         // edges per binA chunk-block
#define NBA   196          // ceil(NE/TA)
#define CAP2R 8960         // per-bucket raw edge capacity (mean 8163, +8.8 sigma)
#define CAP2  9472         // per-bucket capacity incl. self-loops (CAP2R + 512)
#define NBG   782          // gemm blocks in k_front
#define RLN2  1.4426950408889634f

typedef _Float16 half_t;
typedef __attribute__((ext_vector_type(2))) _Float16 f16x2;
typedef __attribute__((ext_vector_type(4))) _Float16 f16x4;
typedef __attribute__((ext_vector_type(8))) _Float16 f16x8;
typedef __attribute__((ext_vector_type(4))) float    f32x4;

__device__ inline float fast_exp2(float x) {
#if __has_builtin(__builtin_amdgcn_exp2f)
  return __builtin_amdgcn_exp2f(x);
#else
  return exp2f(x);
#endif
}

// ============================ k_prep: weight transposes + att-fold rows ============================
// fold rows are PRE-SCALED by 1/ln2 so k_agg can use exp2 directly
// (leaky_relu(c*x) = c*leaky_relu(x) for c>0, so scaling commutes).
__global__ __launch_bounds__(256) void k_prep(const float* __restrict__ W1, const float* __restrict__ W2,
                                              const float* __restrict__ Wc,
                                              const float* __restrict__ as1, const float* __restrict__ ad1,
                                              const float* __restrict__ as2, const float* __restrict__ ad2,
                                              half_t* __restrict__ WT1, half_t* __restrict__ WT2,
                                              half_t* __restrict__ WTc) {
  __shared__ float tile[64][65];
  int b = blockIdx.x, t = threadIdx.x;
  if (b < 10) {
    const float* W; half_t* WT; int k0, n0, N, NTr;
    if (b < 4)      { W = W1; WT = WT1; k0 = (b >> 1) * 64; n0 = (b & 1) * 64; N = 128; NTr = 128; }
    else if (b < 8) { int bb = b - 4; W = W2; WT = WT2; k0 = (bb >> 1) * 64; n0 = (bb & 1) * 64; N = 128; NTr = 128; }
    else            { int bb = b - 8; W = Wc; WT = WTc; k0 = bb * 64; n0 = 0; N = 40; NTr = 48; }
    int col = t & 63, r4 = t >> 6;
#pragma unroll
    for (int i = 0; i < 16; i++) {
      int row = r4 * 16 + i;                       // k-local
      float v = 0.f;
      if (n0 + col < N) v = W[(size_t)(k0 + row) * N + n0 + col];
      tile[row][col] = v;
    }
    __syncthreads();
#pragma unroll
    for (int i = 0; i < 16; i++) {
      int nrow = r4 * 16 + i;                      // n-local
      if (n0 + nrow < NTr) WT[(size_t)(n0 + nrow) * 128 + k0 + col] = (half_t)tile[col][nrow];
    }
    return;
  }
  // fold rows: WT rows 128..135 = (W @ att per head) / ln2; rows 136..143 zero
  const float* W  = (b == 10) ? W1 : W2;
  const float* as = (b == 10) ? as1 : as2;
  const float* ad = (b == 10) ? ad1 : ad2;
  half_t* WT      = (b == 10) ? WT1 : WT2;
  int e = t >> 5, kr = t & 31, h = e & 3;
  const float* att = ((e < 4) ? as : ad) + h * 32;
#pragma unroll
  for (int u = 0; u < 4; u++) {
    int k = u * 32 + kr;
    const float* wrow = W + (size_t)k * 128 + h * 32;
    float s = 0.f;
#pragma unroll
    for (int c = 0; c < 32; c += 4) {
      float4 wv = *(const float4*)(wrow + c);
      float4 av = *(const float4*)(att + c);
      s += wv.x * av.x + wv.y * av.y + wv.z * av.z + wv.w * av.w;
    }
    WT[(size_t)(128 + e) * 128 + k] = (half_t)(s * RLN2);
  }
  for (int u = t; u < 8 * 128; u += 256) WT[(size_t)136 * 128 + u] = (half_t)0.f;
}

// ============================ K1: fused front (byte-identical to r6) ============================
__global__ __launch_bounds__(256) void k_front(const float* __restrict__ X, const half_t* __restrict__ WT1,
                                               half_t* __restrict__ H, float* __restrict__ asrc,
                                               float* __restrict__ adst,
                                               const int* __restrict__ src, const int* __restrict__ dst,
                                               unsigned int* __restrict__ bpk, int* __restrict__ gcnt) {
  __shared__ __align__(16) char smem[36864];
  int t = threadIdx.x;
  int bid = blockIdx.x;

  if (bid < NBA) {
    // ---- binA role ----
    int hb = bid;
    int* hist  = (int*)smem;                  // [196]
    int* hscan = hist + NBK;                  // [196]
    int* cnt   = hscan + NBK;                 // [196] scatter cursor; reused as gbase after scatter
    int* ssc   = cnt + NBK;                   // [256]
    unsigned int* staged = (unsigned int*)(ssc + 256);  // [8192]
    int e0 = hb * TA;
    if (t < NBK) { hist[t] = 0; cnt[t] = 0; }
    __syncthreads();
    for (int i = 0; i < TA / 256; i++) {
      int e = e0 + t + i * 256;
      if (e < NE) atomicAdd(&hist[dst[e] >> BSH], 1);
    }
    __syncthreads();
    // exclusive scan of hist (196 <= 256)
    {
      int v = (t < NBK) ? hist[t] : 0;
      int x = v;
      ssc[t] = x;
      for (int off = 1; off < 256; off <<= 1) {
        __syncthreads();
        int y = (t >= off) ? ssc[t - off] : 0;
        __syncthreads();
        x += y;
        ssc[t] = x;
      }
      if (t < NBK) hscan[t] = x - v;
    }
    __syncthreads();
    for (int i = 0; i < TA / 256; i++) {
      int e = e0 + t + i * 256;
      if (e < NE) {
        int d = dst[e];
        int bk = d >> BSH;
        int pos = hscan[bk] + atomicAdd(&cnt[bk], 1);
        staged[pos] = ((unsigned int)src[e] << BSH) | (unsigned int)(d & (BSZ - 1));
      }
    }
    __syncthreads();
    // ---- concurrent cursor reservation: 196 independent atomics, ONE round-trip ----
    if (t < NBK) {
      int c = hist[t];
      cnt[t] = (c > 0) ? atomicAdd(&gcnt[t], c) : 0;
    }
    __syncthreads();
    // ---- atomic-free flush into contiguous per-bucket region ----
    int wave = t >> 6, lane = t & 63;
    for (int bk = wave; bk < NBK; bk += 4) {
      int c = hist[bk];
      int lo = hscan[bk];
      int base = cnt[bk];
      int avail = CAP2R - base;
      int cw = min(c, max(avail, 0));
      size_t bb = (size_t)bk * CAP2R + base;
      for (int j = lane; j < cw; j += 64) bpk[bb + j] = staged[lo + j];
    }
    return;
  }

  // ---- gemm1 role ----
  half_t* Xt = (half_t*)smem;          // [128][40]
  half_t* Wt = Xt + 128 * 40;          // [144][40]
  int wave = t >> 6, lane = t & 63;
  int l15 = lane & 15, quad = lane >> 4;
  int rb = (bid - NBA) * 128;

  f32x4 acc[2][9];
#pragma unroll
  for (int rt = 0; rt < 2; rt++)
#pragma unroll
    for (int ct = 0; ct < 9; ct++) acc[rt][ct] = (f32x4){0.f, 0.f, 0.f, 0.f};

  for (int k0 = 0; k0 < 128; k0 += 32) {
    __syncthreads();
#pragma unroll
    for (int i = 0; i < 4; i++) {
      int lin = i * 256 + t;
      int row = lin >> 3;
      int c4 = (lin & 7) * 4;
      float4 v = make_float4(0.f, 0.f, 0.f, 0.f);
      int gr = rb + row;
      if (gr < NN) v = *(const float4*)(X + (size_t)gr * 128 + k0 + c4);
      f16x4 hv;
      hv[0] = (half_t)v.x; hv[1] = (half_t)v.y; hv[2] = (half_t)v.z; hv[3] = (half_t)v.w;
      *(f16x4*)(Xt + row * 40 + c4) = hv;
    }
#pragma unroll
    for (int i = 0; i < 3; i++) {
      int lin = i * 256 + t;
      if (lin < 576) {                     // 144 rows x 4 chunks of 8 halves
        int row = lin >> 2;
        int c8 = (lin & 3) * 8;
        *(f16x8*)(Wt + row * 40 + c8) = *(const f16x8*)(WT1 + (size_t)row * 128 + k0 + c8);
      }
    }
    __syncthreads();

    f16x8 a0 = *(const f16x8*)(Xt + (wave * 32 + l15) * 40 + quad * 8);
    f16x8 a1 = *(const f16x8*)(Xt + (wave * 32 + 16 + l15) * 40 + quad * 8);
#pragma unroll
    for (int ct = 0; ct < 9; ct++) {
      f16x8 b = *(const f16x8*)(Wt + (ct * 16 + l15) * 40 + quad * 8);
      acc[0][ct] = __builtin_amdgcn_mfma_f32_16x16x32_f16(a0, b, acc[0][ct], 0, 0, 0);
      acc[1][ct] = __builtin_amdgcn_mfma_f32_16x16x32_f16(a1, b, acc[1][ct], 0, 0, 0);
    }
  }

#pragma unroll
  for (int rt = 0; rt < 2; rt++) {
    int rbase = rb + wave * 32 + rt * 16 + quad * 4;
#pragma unroll
    for (int reg = 0; reg < 4; reg++) {
      int row = rbase + reg;
      if (row < NN) {
#pragma unroll
        for (int ct = 0; ct < 8; ct++) {
          H[(size_t)row * 128 + ct * 16 + l15] = (half_t)acc[rt][ct][reg];
        }
        if (l15 < 8) {
          float v = acc[rt][8][reg];
          if (l15 < 4) asrc[row * 4 + l15] = v;
          else         adst[row * 4 + (l15 - 4)] = v;
        }
      }
    }
  }
}

// ============================ binB (byte-identical to r6) ============================
__global__ __launch_bounds__(512) void k_binB(const unsigned int* __restrict__ bpk,
                                              const int* __restrict__ gcnt,
                                              int* __restrict__ sbeg, int* __restrict__ send,
                                              int* __restrict__ adj) {
  __shared__ int lhist[BSZ];
  __shared__ int lscan[BSZ];
  __shared__ int lcur[BSZ];
  __shared__ int ssc[512];
  __shared__ unsigned int staged[CAP2];
  int b = blockIdx.x;
  int t = threadIdx.x;
  int nbeg = b << BSH;
  int nloc = min(BSZ, NN - nbeg);
  int adjb = b * CAP2;
  int cr = min(gcnt[b], CAP2R);
  size_t rbase = (size_t)b * CAP2R;
  lhist[t] = (t < nloc) ? 1 : 0;           // self-loop in slot 0 of each node's segment
  lcur[t] = 1;
  __syncthreads();
  for (int j = t; j < cr; j += 512) atomicAdd(&lhist[bpk[rbase + j] & (BSZ - 1)], 1);
  __syncthreads();
  {
    int v = lhist[t];
    int x = v;
    ssc[t] = x;
    for (int off = 1; off < 512; off <<= 1) {
      __syncthreads();
      int y = (t >= off) ? ssc[t - off] : 0;
      __syncthreads();
      x += y;
      ssc[t] = x;
    }
    lscan[t] = x - v;
  }
  __syncthreads();
  int total = lscan[BSZ - 1] + lhist[BSZ - 1];
  if (t < nloc) {
    int bg = adjb + lscan[t];
    sbeg[nbeg + t] = bg;
    send[nbeg + t] = bg + lhist[t];
    staged[lscan[t]] = (unsigned int)(nbeg + t);
  }
  __syncthreads();
  for (int j = t; j < cr; j += 512) {
    unsigned int v = bpk[rbase + j];
    int dl = v & (BSZ - 1);
    int idx = lscan[dl] + atomicAdd(&lcur[dl], 1);
    if (idx < CAP2) staged[idx] = v >> BSH;
  }
  __syncthreads();
  int lim = min(total, CAP2);
  for (int i = t; i < lim; i += 512) adj[adjb + i] = (int)staged[i];
}

// ============================ aggregation: 8 edges in flight + 1-deep H pipeline ============
// one wave per dst node; 8 lanes x 16ch per edge; asrc/adj 1-ahead AND H-row 1-ahead.
// logits are pre-scaled by 1/ln2 -> exp2 (1 transcendental, no mul).
__global__ __launch_bounds__(256) void k_agg(const half_t* __restrict__ H, const int* __restrict__ sbeg,
                                             const int* __restrict__ send, const int* __restrict__ adj,
                                             const float* __restrict__ asrc, const float* __restrict__ adst,
                                             const float* __restrict__ bias, half_t* __restrict__ out) {
  int n = blockIdx.x * 4 + (threadIdx.x >> 6);
  if (n >= NN) return;
  int lane = threadIdx.x & 63;
  int sub = lane & 7;              // 16-channel slice [sub*16, sub*16+16)
  int g = lane >> 3;               // edge group [0,8)
  int head = sub >> 1;
  float ad = adst[(size_t)n * 4 + head];
  float acc[16];
#pragma unroll
  for (int j = 0; j < 16; j++) acc[j] = 0.f;
  float wsum = 0.f;
  int beg = sbeg[n], end = send[n];
  int i = beg + g;
  int s = 0;
  float a = 0.f;
  f16x8 h0 = (f16x8)(half_t)0, h1 = (f16x8)(half_t)0;
  if (i < end) {
    s = adj[i];
    a = asrc[(size_t)s * 4 + head];
    const f16x8* hp = (const f16x8*)(H + (size_t)s * 128 + sub * 16);
    h0 = hp[0]; h1 = hp[1];
  }
  while (i < end) {
    int inext = i + 8;
    int sn = 0;
    float an = 0.f;
    if (inext < end) {             // prefetch next edge's index + logit
      sn = adj[inext];
      an = asrc[(size_t)sn * 4 + head];
    }
    // prefetch next edge's H row (sn=0 dummy when past end: reads valid H[0])
    const f16x8* hpn = (const f16x8*)(H + (size_t)sn * 128 + sub * 16);
    f16x8 g0 = hpn[0], g1 = hpn[1];
    // compute current edge
    float ev = a + ad;
    ev = (ev > 0.f) ? ev : 0.2f * ev;
    float w = fast_exp2(ev);
    wsum += w;
#pragma unroll
    for (int j = 0; j < 8; j++) acc[j] += w * (float)h0[j];
#pragma unroll
    for (int j = 0; j < 8; j++) acc[8 + j] += w * (float)h1[j];
    s = sn; a = an; h0 = g0; h1 = g1; i = inext;
  }
  // combine the 8 edge-groups (lane bits 3..5)
#pragma unroll
  for (int m = 8; m < 64; m <<= 1) {
    wsum += __shfl_xor(wsum, m, 64);
#pragma unroll
    for (int j = 0; j < 16; j++) acc[j] += __shfl_xor(acc[j], m, 64);
  }
  float scale = 1.0f / (wsum + 1e-16f);
  float o0 = acc[0], o1 = acc[1];
#pragma unroll
  for (int r = 1; r < 8; r++) {
    if (g == r) { o0 = acc[2 * r]; o1 = acc[2 * r + 1]; }
  }
  int ch = sub * 16 + g * 2;
  o0 = fmaxf(o0 * scale + bias[ch], 0.f);
  o1 = fmaxf(o1 * scale + bias[ch + 1], 0.f);
  f16x2 o;
  o[0] = (half_t)o0;
  o[1] = (half_t)o1;
  *(f16x2*)(out + (size_t)n * 128 + ch) = o;
}

// ============================ MFMA GEMM, 64-row tiles (1563 blocks ~ 6/CU) ==========
__global__ __launch_bounds__(256) void k_gemm_att(const half_t* __restrict__ X, const half_t* __restrict__ WT,
                                                  half_t* __restrict__ H, float* __restrict__ asrc,
                                                  float* __restrict__ adst) {
  __shared__ __align__(16) half_t Xt[64 * 40];
  __shared__ __align__(16) half_t Wt[144 * 40];
  int t = threadIdx.x;
  int wave = t >> 6, lane = t & 63;
  int l15 = lane & 15, quad = lane >> 4;
  int rb = blockIdx.x * 64;

  f32x4 acc[9];
#pragma unroll
  for (int ct = 0; ct < 9; ct++) acc[ct] = (f32x4){0.f, 0.f, 0.f, 0.f};

  for (int k0 = 0; k0 < 128; k0 += 32) {
    __syncthreads();
    {
      int row = t >> 2;                    // 64 rows x 4 chunks of 8 halves
      int c8 = (t & 3) * 8;
      f16x8 hv = (f16x8)(half_t)0;
      int gr = rb + row;
      if (gr < NN) hv = *(const f16x8*)(X + (size_t)gr * 128 + k0 + c8);
      *(f16x8*)(Xt + row * 40 + c8) = hv;
    }
#pragma unroll
    for (int i = 0; i < 3; i++) {
      int lin = i * 256 + t;
      if (lin < 576) {                     // 144 rows x 4 chunks
        int row = lin >> 2;
        int c8 = (lin & 3) * 8;
        *(f16x8*)(Wt + row * 40 + c8) = *(const f16x8*)(WT + (size_t)row * 128 + k0 + c8);
      }
    }
    __syncthreads();

    f16x8 a0 = *(const f16x8*)(Xt + (wave * 16 + l15) * 40 + quad * 8);
#pragma unroll
    for (int ct = 0; ct < 9; ct++) {
      f16x8 b = *(const f16x8*)(Wt + (ct * 16 + l15) * 40 + quad * 8);
      acc[ct] = __builtin_amdgcn_mfma_f32_16x16x32_f16(a0, b, acc[ct], 0, 0, 0);
    }
  }

  int rbase = rb + wave * 16 + quad * 4;
#pragma unroll
  for (int reg = 0; reg < 4; reg++) {
    int row = rbase + reg;
    if (row < NN) {
#pragma unroll
      for (int ct = 0; ct < 8; ct++) {
        H[(size_t)row * 128 + ct * 16 + l15] = (half_t)acc[ct][reg];
      }
      if (l15 < 8) {
        float v = acc[8][reg];
        if (l15 < 4) asrc[row * 4 + l15] = v;
        else         adst[row * 4 + (l15 - 4)] = v;
      }
    }
  }
}

// ============================ classifier, 64-row tiles ============================
__global__ __launch_bounds__(256) void k_classifier(const half_t* __restrict__ Hf, const half_t* __restrict__ WTc,
                                                    const float* __restrict__ bc, float* __restrict__ out) {
  __shared__ __align__(16) half_t Xt[64 * 40];
  __shared__ __align__(16) half_t Wt[48 * 40];
  int t = threadIdx.x;
  int wave = t >> 6, lane = t & 63;
  int l15 = lane & 15, quad = lane >> 4;
  int rb = blockIdx.x * 64;

  f32x4 acc[3];
#pragma unroll
  for (int ct = 0; ct < 3; ct++) acc[ct] = (f32x4){0.f, 0.f, 0.f, 0.f};

  for (int k0 = 0; k0 < 128; k0 += 32) {
    __syncthreads();
    {
      int row = t >> 2;
      int c8 = (t & 3) * 8;
      f16x8 hv = (f16x8)(half_t)0;
      int gr = rb + row;
      if (gr < NN) hv = *(const f16x8*)(Hf + (size_t)gr * 128 + k0 + c8);
      *(f16x8*)(Xt + row * 40 + c8) = hv;
    }
    if (t < 192) {
      int row = t >> 2;
      int c8 = (t & 3) * 8;
      *(f16x8*)(Wt + row * 40 + c8) = *(const f16x8*)(WTc + (size_t)row * 128 + k0 + c8);
    }
    __syncthreads();

    f16x8 a0 = *(const f16x8*)(Xt + (wave * 16 + l15) * 40 + quad * 8);
#pragma unroll
    for (int ct = 0; ct < 3; ct++) {
      f16x8 b = *(const f16x8*)(Wt + (ct * 16 + l15) * 40 + quad * 8);
      acc[ct] = __builtin_amdgcn_mfma_f32_16x16x32_f16(a0, b, acc[ct], 0, 0, 0);
    }
  }

#pragma unroll
  for (int ct = 0; ct < 3; ct++) {
    int col = ct * 16 + l15;
    if (col < 40) {
      float bv = bc[col];
#pragma unroll
      for (int reg = 0; reg < 4; reg++) {
        int row = rb + wave * 16 + quad * 4 + reg;
        if (row < NN) out[(size_t)row * 40 + col] = acc[ct][reg] + bv;
      }
    }
  }
}

// ============================ launch ============================

extern "C" void kernel_launch(void* const* d_in, const int* in_sizes, int n_in,
                              void* d_out, int out_size, void* d_ws, size_t ws_size,
                              hipStream_t stream) {
  const float* x   = (const float*)d_in[0];
  const int*   ei  = (const int*)d_in[1];
  const float* W1  = (const float*)d_in[2];
  const float* as1 = (const float*)d_in[3];
  const float* ad1 = (const float*)d_in[4];
  const float* b1  = (const float*)d_in[5];
  const float* W2  = (const float*)d_in[6];
  const float* as2 = (const float*)d_in[7];
  const float* ad2 = (const float*)d_in[8];
  const float* b2  = (const float*)d_in[9];
  const float* Wc  = (const float*)d_in[10];
  const float* bc  = (const float*)d_in[11];
  float* out = (float*)d_out;

  const int* esrc = ei;
  const int* edst = ei + NE;

  char* w = (char*)d_ws;
  auto alloc = [&](size_t bytes) {
    void* p = (void*)w;
    w += (bytes + 255) & ~(size_t)255;
    return p;
  };
  half_t* A   = (half_t*)alloc(sizeof(half_t) * (size_t)NN * 128);  // gather target
  half_t* B   = (half_t*)alloc(sizeof(half_t) * (size_t)NN * 128);  // layer output
  float* asrc = (float*)alloc(sizeof(float) * (size_t)NN * 4);
  float* adst = (float*)alloc(sizeof(float) * (size_t)NN * 4);
  int* sbeg   = (int*)alloc(sizeof(int) * NN);
  int* send   = (int*)alloc(sizeof(int) * NN);
  unsigned int* bpk = (unsigned int*)alloc(sizeof(unsigned int) * (size_t)NBK * CAP2R);
  int* gcnt   = (int*)alloc(sizeof(int) * NBK);
  int* adj    = (int*)alloc(sizeof(int) * (size_t)NBK * CAP2);
  half_t* WT1 = (half_t*)alloc(sizeof(half_t) * 144 * 128);
  half_t* WT2 = (half_t*)alloc(sizeof(half_t) * 144 * 128);
  half_t* WTc = (half_t*)alloc(sizeof(half_t) * 48 * 128);

  // ---- zero per-bucket cursors ----
  hipMemsetAsync(gcnt, 0, sizeof(int) * NBK, stream);

  // ---- weight prep (WT1/WT2 fold rows pre-scaled by 1/ln2; WTc) ----
  k_prep<<<12, 256, 0, stream>>>(W1, W2, Wc, as1, ad1, as2, ad2, WT1, WT2, WTc);

  // ---- fused front: binA binning + gemm1 ----
  k_front<<<NBA + NBG, 256, 0, stream>>>(x, WT1, A, asrc, adst, esrc, edst, bpk, gcnt);

  // ---- CSR finalize ----
  k_binB<<<NBK, 512, 0, stream>>>(bpk, gcnt, sbeg, send, adj);

  // ---- layer 1 aggregate ----
  k_agg<<<(NN + 3) / 4, 256, 0, stream>>>(A, sbeg, send, adj, asrc, adst, b1, B);

  // ---- layer 2 ----
  k_gemm_att<<<(NN + 63) / 64, 256, 0, stream>>>(B, WT2, A, asrc, adst);
  k_agg<<<(NN + 3) / 4, 256, 0, stream>>>(A, sbeg, send, adj, asrc, adst, b2, B);

  // ---- classifier ----
  k_classifier<<<(NN + 63) / 64, 256, 0, stream>>>(B, WTc, bc, out);
}